// Round 5
// baseline (138.353 us; speedup 1.0000x reference)
//
#include <hip/hip_runtime.h>
#include <hip/hip_bf16.h>

typedef __bf16 bf16_t;
typedef __bf16 bf16x8 __attribute__((ext_vector_type(8)));
typedef float f32x4 __attribute__((ext_vector_type(4)));
typedef float f32x2 __attribute__((ext_vector_type(2)));

#define B_   2
#define N_   16384
#define S_   4096
#define DS_  128
#define DT_  256
#define CIN_ 384
#define C0_  256
#define C1_  128
#define M_   (B_*N_)      // 32768 points total
#define NCH_ 32
#define SCH_ (S_/NCH_)    // 128 targets per chunk

__device__ __forceinline__ void gl_lds16(const void* g, void* l) {
  __builtin_amdgcn_global_load_lds((const __attribute__((address_space(1))) void*)g,
                                   (__attribute__((address_space(3))) void*)l, 16, 0, 0);
}

// ---- packed fp32 helpers (bitwise-identical IEEE rn per half) ----
__device__ __forceinline__ f32x2 pk_mul_sv(double a, f32x2 b) {   // {a.lo*b.lo, a.hi*b.hi}
  f32x2 d; asm("v_pk_mul_f32 %0, %1, %2" : "=v"(d) : "s"(a), "v"(b)); return d;
}
__device__ __forceinline__ f32x2 pk_add_sv(double a, f32x2 b) {
  f32x2 d; asm("v_pk_add_f32 %0, %1, %2" : "=v"(d) : "s"(a), "v"(b)); return d;
}
__device__ __forceinline__ f32x2 pk_mul_vv(f32x2 a, f32x2 b) {
  f32x2 d; asm("v_pk_mul_f32 %0, %1, %2" : "=v"(d) : "v"(a), "v"(b)); return d;
}
__device__ __forceinline__ f32x2 pk_add_vv(f32x2 a, f32x2 b) {
  f32x2 d; asm("v_pk_add_f32 %0, %1, %2" : "=v"(d) : "v"(a), "v"(b)); return d;
}
__device__ __forceinline__ f32x2 pk_sub_vv(f32x2 a, f32x2 b) {    // a - b (exact negate-add)
  f32x2 d; asm("v_pk_add_f32 %0, %1, %2 neg_lo:[0,1] neg_hi:[0,1]" : "=v"(d) : "v"(a), "v"(b)); return d;
}

// branchy top-3 insert with exact lexicographic (d, idx) strict-less (small merges only)
__device__ __forceinline__ void lins3(float d, int ix,
                                      float& d0, float& d1, float& d2,
                                      int& i0, int& i1, int& i2) {
  if (d < d2 || (d == d2 && ix < i2)) {
    d2 = d; i2 = ix;
    if (d2 < d1 || (d2 == d1 && i2 < i1)) {
      float td = d1; d1 = d2; d2 = td; int ti = i1; i1 = i2; i2 = ti;
      if (d1 < d0 || (d1 == d0 && i1 < i0)) {
        td = d0; d0 = d1; d1 = td; ti = i0; i0 = i1; i1 = ti;
      }
    }
  }
}

// branchless sorted-insert: distances via min/med3, indices via cmp-on-old-state.
// strict < + ascending candidate index => top_k-stable.
__device__ __forceinline__ void bins3(float d, int jx,
                                      float& e0, float& e1, float& e2,
                                      int& x0, int& x1, int& x2) {
  int t2i = (d < e1) ? x1 : jx;
  int nI2 = (d < e2) ? t2i : x2;
  int t1i = (d < e0) ? x0 : jx;
  int nI1 = (d < e1) ? t1i : x1;
  int nI0 = (d < e0) ? jx  : x0;
  float nD2 = __builtin_amdgcn_fmed3f(e1, e2, d);
  float nD1 = __builtin_amdgcn_fmed3f(e0, e1, d);
  float nD0 = fminf(e0, d);
  x0 = nI0; x1 = nI1; x2 = nI2;
  e0 = nD0; e1 = nD1; e2 = nD2;
}

// ---------------- weights fp32->bf16 + target pair-SoA pack ----------------
// tgtp layout: per pair q: 4 doubles = {x0,x1},{y0,y1},{z0,z1},{t20,t21}
__global__ void k_misc(const float* __restrict__ xyz_t, double* __restrict__ tgtp,
                       const float* __restrict__ w0, const float* __restrict__ w1,
                       bf16_t* __restrict__ w0b, bf16_t* __restrict__ w1b) {
  int i = blockIdx.x * 256 + threadIdx.x;          // 98304 threads
  if (i < C0_*CIN_) w0b[i] = (bf16_t)w0[i];
  if (i < C1_*C0_)  w1b[i] = (bf16_t)w1[i];
  if (i < B_*S_/2) {
    const float* q = xyz_t + (size_t)i*6;
    float x0=q[0], y0=q[1], z0=q[2], x1=q[3], y1=q[4], z1=q[5];
    float t20 = __fadd_rn(__fadd_rn(__fmul_rn(x0,x0), __fmul_rn(y0,y0)), __fmul_rn(z0,z0));
    float t21 = __fadd_rn(__fadd_rn(__fmul_rn(x1,x1), __fmul_rn(y1,y1)), __fmul_rn(z1,z1));
    f32x2 px = {x0,x1}, py = {y0,y1}, pz = {z0,z1}, pw = {t20,t21};
    double* o = tgtp + (size_t)i*4;
    o[0] = __builtin_bit_cast(double, px);
    o[1] = __builtin_bit_cast(double, py);
    o[2] = __builtin_bit_cast(double, pz);
    o[3] = __builtin_bit_cast(double, pw);
  }
}

// ---------------- 3-NN over one target chunk (packed fp32) ----------------
// Exact numpy fp32 order per half: d = (s2 + t2) - 2*((sx tx + sy ty) + sz tz)
// Targets as uniform doubles in SGPR pairs; 2 chains (even/odd candidates).
__global__ __launch_bounds__(256) void k_knn(const float* __restrict__ xyz_s,
                                             const double* __restrict__ tgtp,
                                             float* __restrict__ pd, int* __restrict__ pi) {
  const int b = blockIdx.z, ch = blockIdx.y;
  const int n = blockIdx.x * 256 + threadIdx.x;
  const int s0 = ch * SCH_;
  const double* tp = tgtp + ((size_t)b*(S_/2) + ch*(SCH_/2))*4;   // uniform base
  const float* ps = xyz_s + ((size_t)b*N_ + n)*3;
  const float sx = ps[0], sy = ps[1], sz = ps[2];
  const float s2 = __fadd_rn(__fadd_rn(__fmul_rn(sx,sx), __fmul_rn(sy,sy)), __fmul_rn(sz,sz));
  const f32x2 sxx = {sx,sx}, syy = {sy,sy}, szz = {sz,sz}, s22 = {s2,s2}, two2 = {2.f,2.f};

  float eA0=3.4e38f, eA1=3.4e38f, eA2=3.4e38f, eB0=3.4e38f, eB1=3.4e38f, eB2=3.4e38f;
  int   xA0=0, xA1=0, xA2=0, xB0=0, xB1=0, xB2=0;

  #pragma unroll 4
  for (int q = 0; q < SCH_/2; ++q) {
    double X = tp[q*4+0], Y = tp[q*4+1], Z = tp[q*4+2], W = tp[q*4+3];
    f32x2 dot = pk_add_vv(pk_add_vv(pk_mul_sv(X, sxx), pk_mul_sv(Y, syy)), pk_mul_sv(Z, szz));
    f32x2 st  = pk_add_sv(W, s22);                 // t2 + s2 (commutative, bitwise same)
    f32x2 d2  = pk_sub_vv(st, pk_mul_vv(two2, dot));
    bins3(d2.x, 2*q,   eA0, eA1, eA2, xA0, xA1, xA2);  // even candidates
    bins3(d2.y, 2*q+1, eB0, eB1, eB2, xB0, xB1, xB2);  // odd candidates
  }

  // merge 2 chains (6 candidates) with exact lexicographic comparator
  float e0 = eA0, e1 = eA1, e2 = eA2;
  int   x0 = xA0, x1 = xA1, x2 = xA2;
  lins3(eB0, xB0, e0, e1, e2, x0, x1, x2);
  lins3(eB1, xB1, e0, e1, e2, x0, x1, x2);
  lins3(eB2, xB2, e0, e1, e2, x0, x1, x2);

  // chunk-major layout: fully coalesced writes (and coalesced merge reads)
  size_t base = ((size_t)ch*M_ + (size_t)b*N_ + n)*3;
  pd[base+0] = e0; pd[base+1] = e1; pd[base+2] = e2;
  pi[base+0] = s0+x0; pi[base+1] = s0+x1; pi[base+2] = s0+x2;
}

// ---------------- merge chunk candidates, compute inverse-distance weights ----------------
__global__ void k_merge(const float* __restrict__ pd, const int* __restrict__ pi,
                        float* __restrict__ wgt, int* __restrict__ widx) {
  int p = blockIdx.x * 256 + threadIdx.x;  // 0..32767
  float e0 = 3.4e38f, e1 = 3.4e38f, e2 = 3.4e38f;
  int   x0 = 0, x1 = 0, x2 = 0;
  for (int ch = 0; ch < NCH_; ++ch) {      // ascending chunk = ascending target index
    size_t base = ((size_t)ch*M_ + p)*3;
    #pragma unroll
    for (int k = 0; k < 3; ++k)
      bins3(pd[base+k], pi[base+k], e0, e1, e2, x0, x1, x2);
  }
  float r0 = 1.f/(e0 + 1e-8f), r1 = 1.f/(e1 + 1e-8f), r2 = 1.f/(e2 + 1e-8f);
  float s = r0 + r1 + r2;
  wgt[p*3+0] = r0/s; wgt[p*3+1] = r1/s; wgt[p*3+2] = r2/s;
  widx[p*3+0] = x0;  widx[p*3+1] = x1;  widx[p*3+2] = x2;
}

// ---------------- gather + interpolate + concat -> features (bf16, [M][384]) ----------------
__global__ __launch_bounds__(256) void k_gather(const float* __restrict__ feats_s,
                                                const float* __restrict__ feats_t,
                                                const float* __restrict__ wgt,
                                                const int* __restrict__ widx,
                                                bf16_t* __restrict__ features) {
  const int g = threadIdx.x >> 5, lane = threadIdx.x & 31;
  const int p = blockIdx.x * 8 + g;
  const int b = p >> 14;                       // N_ = 2^14
  const float w0 = wgt[p*3+0], w1 = wgt[p*3+1], w2 = wgt[p*3+2];
  const int   j0 = widx[p*3+0], j1 = widx[p*3+1], j2 = widx[p*3+2];
  const float* f0 = feats_t + ((size_t)b*S_ + j0)*DT_;
  const float* f1 = feats_t + ((size_t)b*S_ + j1)*DT_;
  const float* f2 = feats_t + ((size_t)b*S_ + j2)*DT_;
  const float* fs = feats_s + (size_t)p*DS_;
  bf16_t* out = features + (size_t)p*CIN_;
  const int c0 = lane * 8;
  if (lane < 16) {
    float4 a = *(const float4*)(fs + c0);
    float4 bv = *(const float4*)(fs + c0 + 4);
    bf16x8 o;
    o[0]=(bf16_t)a.x;  o[1]=(bf16_t)a.y;  o[2]=(bf16_t)a.z;  o[3]=(bf16_t)a.w;
    o[4]=(bf16_t)bv.x; o[5]=(bf16_t)bv.y; o[6]=(bf16_t)bv.z; o[7]=(bf16_t)bv.w;
    *(bf16x8*)(out + c0) = o;
  }
  {
    float4 a0 = *(const float4*)(f0 + c0), a1 = *(const float4*)(f0 + c0 + 4);
    float4 b0 = *(const float4*)(f1 + c0), b1 = *(const float4*)(f1 + c0 + 4);
    float4 cc0= *(const float4*)(f2 + c0), cc1= *(const float4*)(f2 + c0 + 4);
    bf16x8 o;
    o[0]=(bf16_t)(w0*a0.x + w1*b0.x + w2*cc0.x);
    o[1]=(bf16_t)(w0*a0.y + w1*b0.y + w2*cc0.y);
    o[2]=(bf16_t)(w0*a0.z + w1*b0.z + w2*cc0.z);
    o[3]=(bf16_t)(w0*a0.w + w1*b0.w + w2*cc0.w);
    o[4]=(bf16_t)(w0*a1.x + w1*b1.x + w2*cc1.x);
    o[5]=(bf16_t)(w0*a1.y + w1*b1.y + w2*cc1.y);
    o[6]=(bf16_t)(w0*a1.z + w1*b1.z + w2*cc1.z);
    o[7]=(bf16_t)(w0*a1.w + w1*b1.w + w2*cc1.w);
    *(bf16x8*)(out + DS_ + c0) = o;
  }
}

// ---------------- GEMM1: x0[M][256] = features[M][384] @ w0^T + b0 (bf16 MFMA) ----------------
__global__ __launch_bounds__(256) void k_gemm1(const bf16_t* __restrict__ A,
                                               const bf16_t* __restrict__ Bw,
                                               const float* __restrict__ bias,
                                               bf16_t* __restrict__ X0,
                                               float* __restrict__ psum, float* __restrict__ psq) {
  __shared__ __align__(16) bf16_t As[128*32];
  __shared__ __align__(16) bf16_t Bs[128*32];
  __shared__ float lsA[256*4], lqA[256*4];
  const int tid = threadIdx.x, w = tid >> 6, l = tid & 63;
  const int bx = blockIdx.x, by = blockIdx.y;
  const int m0 = bx*128, n0 = by*128;
  const int wr = w >> 1, wc = w & 1, l15 = l & 15, l4 = l >> 4;
  f32x4 acc[4][4];
  #pragma unroll
  for (int i = 0; i < 4; ++i)
    #pragma unroll
    for (int j = 0; j < 4; ++j) acc[i][j] = (f32x4){0.f,0.f,0.f,0.f};

  for (int step = 0; step < CIN_/32; ++step) {
    const int k0 = step*32;
    #pragma unroll
    for (int i = 0; i < 2; ++i) {
      int row = w*32 + i*16 + (l >> 2);
      int ke  = k0 + (l & 3)*8;
      gl_lds16(A  + (size_t)(m0+row)*CIN_ + ke, &As[row*32 + (l&3)*8]);
      gl_lds16(Bw + (size_t)(n0+row)*CIN_ + ke, &Bs[row*32 + (l&3)*8]);
    }
    asm volatile("s_waitcnt vmcnt(0)" ::: "memory");
    __syncthreads();
    bf16x8 af[4], bfr[4];
    #pragma unroll
    for (int mi = 0; mi < 4; ++mi) af[mi]  = *(const bf16x8*)&As[(wr*64 + mi*16 + l15)*32 + l4*8];
    #pragma unroll
    for (int ni = 0; ni < 4; ++ni) bfr[ni] = *(const bf16x8*)&Bs[(wc*64 + ni*16 + l15)*32 + l4*8];
    #pragma unroll
    for (int mi = 0; mi < 4; ++mi)
      #pragma unroll
      for (int ni = 0; ni < 4; ++ni)
        acc[mi][ni] = __builtin_amdgcn_mfma_f32_16x16x32_bf16(af[mi], bfr[ni], acc[mi][ni], 0, 0, 0);
    __syncthreads();
  }

  float ls[4] = {0,0,0,0}, lq[4] = {0,0,0,0};
  #pragma unroll
  for (int ni = 0; ni < 4; ++ni) {
    int col = n0 + wc*64 + ni*16 + l15;
    float bcol = bias[col];
    #pragma unroll
    for (int mi = 0; mi < 4; ++mi) {
      int rbase = m0 + wr*64 + mi*16 + l4*4;
      #pragma unroll
      for (int r = 0; r < 4; ++r) {
        float v = acc[mi][ni][r] + bcol;
        X0[(size_t)(rbase + r)*C0_ + col] = (bf16_t)v;
        ls[ni] += v; lq[ni] += v*v;
      }
    }
  }
  #pragma unroll
  for (int ni = 0; ni < 4; ++ni) { lsA[tid*4+ni] = ls[ni]; lqA[tid*4+ni] = lq[ni]; }
  __syncthreads();
  if (tid < 128) {
    int c = tid, wcc = c >> 6, nii = (c >> 4) & 3, ll = c & 15;
    float s = 0.f, q = 0.f;
    #pragma unroll
    for (int wrr = 0; wrr < 2; ++wrr)
      #pragma unroll
      for (int g4 = 0; g4 < 4; ++g4) {
        int t = (wrr*2 + wcc)*64 + g4*16 + ll;
        s += lsA[t*4 + nii]; q += lqA[t*4 + nii];
      }
    int pb = (bx*2 + by)*128 + c;
    psum[pb] = s; psq[pb] = q;
  }
}

// ---------------- BN0 stats finalize: one block per channel ----------------
__global__ __launch_bounds__(256) void k_fin0(const float* __restrict__ psum, const float* __restrict__ psq,
                       const float* __restrict__ gamma, const float* __restrict__ beta,
                       float* __restrict__ scale, float* __restrict__ shift) {
  __shared__ float sw[4], qw[4];
  int c = blockIdx.x, t = threadIdx.x;       // 256 blocks, 256 threads
  int nt = c >> 7, cl = c & 127;
  int ix = (t*2 + nt)*128 + cl;
  float s = psum[ix], q = psq[ix];
  #pragma unroll
  for (int o = 32; o; o >>= 1) { s += __shfl_down(s, o, 64); q += __shfl_down(q, o, 64); }
  if ((t & 63) == 0) { sw[t>>6] = s; qw[t>>6] = q; }
  __syncthreads();
  if (t == 0) {
    s = (sw[0]+sw[1])+(sw[2]+sw[3]); q = (qw[0]+qw[1])+(qw[2]+qw[3]);
    float mean = s / (float)M_;
    float var  = q / (float)M_ - mean*mean;
    float sc = gamma[c] * rsqrtf(var + 1e-5f);
    scale[c] = sc; shift[c] = beta[c] - mean*sc;
  }
}

// ---------------- GEMM2: x1[M][128] = relu(BN0(x0)) @ w1^T + b1 ----------------
__global__ __launch_bounds__(256) void k_gemm2(const bf16_t* __restrict__ X0,
                                               const bf16_t* __restrict__ Bw,
                                               const float* __restrict__ scale,
                                               const float* __restrict__ shift,
                                               const float* __restrict__ bias,
                                               bf16_t* __restrict__ X1,
                                               float* __restrict__ psum, float* __restrict__ psq) {
  __shared__ __align__(16) bf16_t As[128*32];
  __shared__ __align__(16) bf16_t Bs[128*32];
  __shared__ float scl[C0_], shl[C0_];
  __shared__ float lsA[256*4], lqA[256*4];
  const int tid = threadIdx.x, w = tid >> 6, l = tid & 63;
  const int m0 = blockIdx.x * 128;
  const int wr = w >> 1, wc = w & 1, l15 = l & 15, l4 = l >> 4;
  scl[tid] = scale[tid]; shl[tid] = shift[tid];
  f32x4 acc[4][4];
  #pragma unroll
  for (int i = 0; i < 4; ++i)
    #pragma unroll
    for (int j = 0; j < 4; ++j) acc[i][j] = (f32x4){0.f,0.f,0.f,0.f};
  __syncthreads();

  for (int step = 0; step < C0_/32; ++step) {
    const int k0 = step*32;
    #pragma unroll
    for (int i = 0; i < 2; ++i) {
      int row = w*32 + i*16 + (l >> 2);
      gl_lds16(Bw + (size_t)row*C0_ + k0 + (l&3)*8, &Bs[row*32 + (l&3)*8]);
    }
    #pragma unroll
    for (int i = 0; i < 2; ++i) {
      int ci = i*256 + tid;
      int row = ci >> 2, ke = (ci & 3)*8;
      bf16x8 v = *(const bf16x8*)(X0 + (size_t)(m0+row)*C0_ + k0 + ke);
      bf16x8 o;
      #pragma unroll
      for (int j = 0; j < 8; ++j) {
        int k = k0 + ke + j;
        float f = fmaxf(fmaf((float)v[j], scl[k], shl[k]), 0.f);
        o[j] = (bf16_t)f;
      }
      *(bf16x8*)&As[row*32 + ke] = o;
    }
    asm volatile("s_waitcnt vmcnt(0)" ::: "memory");
    __syncthreads();
    bf16x8 af[4], bfr[4];
    #pragma unroll
    for (int mi = 0; mi < 4; ++mi) af[mi]  = *(const bf16x8*)&As[(wr*64 + mi*16 + l15)*32 + l4*8];
    #pragma unroll
    for (int ni = 0; ni < 4; ++ni) bfr[ni] = *(const bf16x8*)&Bs[(wc*64 + ni*16 + l15)*32 + l4*8];
    #pragma unroll
    for (int mi = 0; mi < 4; ++mi)
      #pragma unroll
      for (int ni = 0; ni < 4; ++ni)
        acc[mi][ni] = __builtin_amdgcn_mfma_f32_16x16x32_bf16(af[mi], bfr[ni], acc[mi][ni], 0, 0, 0);
    __syncthreads();
  }

  float ls[4] = {0,0,0,0}, lq[4] = {0,0,0,0};
  #pragma unroll
  for (int ni = 0; ni < 4; ++ni) {
    int col = wc*64 + ni*16 + l15;
    float bcol = bias[col];
    #pragma unroll
    for (int mi = 0; mi < 4; ++mi) {
      int rbase = m0 + wr*64 + mi*16 + l4*4;
      #pragma unroll
      for (int r = 0; r < 4; ++r) {
        float v = acc[mi][ni][r] + bcol;
        X1[(size_t)(rbase + r)*C1_ + col] = (bf16_t)v;
        ls[ni] += v; lq[ni] += v*v;
      }
    }
  }
  #pragma unroll
  for (int ni = 0; ni < 4; ++ni) { lsA[tid*4+ni] = ls[ni]; lqA[tid*4+ni] = lq[ni]; }
  __syncthreads();
  if (tid < 128) {
    int c = tid, wcc = c >> 6, nii = (c >> 4) & 3, ll = c & 15;
    float s = 0.f, q = 0.f;
    #pragma unroll
    for (int wrr = 0; wrr < 2; ++wrr)
      #pragma unroll
      for (int g4 = 0; g4 < 4; ++g4) {
        int t = (wrr*2 + wcc)*64 + g4*16 + ll;
        s += lsA[t*4 + nii]; q += lqA[t*4 + nii];
      }
    psum[blockIdx.x*128 + c] = s; psq[blockIdx.x*128 + c] = q;
  }
}

// ---------------- BN1 stats finalize: one block per channel ----------------
__global__ __launch_bounds__(256) void k_fin1(const float* __restrict__ psum, const float* __restrict__ psq,
                       const float* __restrict__ gamma, const float* __restrict__ beta,
                       float* __restrict__ scale, float* __restrict__ shift) {
  __shared__ float sw[4], qw[4];
  int c = blockIdx.x, t = threadIdx.x;       // 128 blocks, 256 threads
  int ix = t*128 + c;
  float s = psum[ix], q = psq[ix];
  #pragma unroll
  for (int o = 32; o; o >>= 1) { s += __shfl_down(s, o, 64); q += __shfl_down(q, o, 64); }
  if ((t & 63) == 0) { sw[t>>6] = s; qw[t>>6] = q; }
  __syncthreads();
  if (t == 0) {
    s = (sw[0]+sw[1])+(sw[2]+sw[3]); q = (qw[0]+qw[1])+(qw[2]+qw[3]);
    float mean = s / (float)M_;
    float var  = q / (float)M_ - mean*mean;
    float sc = gamma[c] * rsqrtf(var + 1e-5f);
    scale[c] = sc; shift[c] = beta[c] - mean*sc;
  }
}

// ---------------- apply BN1 + ReLU -> fp32 output ----------------
__global__ __launch_bounds__(256) void k_apply(const bf16_t* __restrict__ X1,
                                               const float* __restrict__ scale,
                                               const float* __restrict__ shift,
                                               float* __restrict__ out) {
  int t = blockIdx.x * 256 + threadIdx.x;
  size_t base = (size_t)t * 8;
  bf16x8 v = *(const bf16x8*)(X1 + base);
  int c0 = (t & 15) * 8;
  #pragma unroll
  for (int j = 0; j < 8; ++j) {
    float f = fmaf((float)v[j], scale[c0+j], shift[c0+j]);
    out[base + j] = fmaxf(f, 0.f);
  }
}

extern "C" void kernel_launch(void* const* d_in, const int* in_sizes, int n_in,
                              void* d_out, int out_size, void* d_ws, size_t ws_size,
                              hipStream_t stream) {
  (void)in_sizes; (void)n_in; (void)out_size; (void)ws_size;
  const float* xyz_s   = (const float*)d_in[0];
  const float* xyz_t   = (const float*)d_in[1];
  const float* feats_s = (const float*)d_in[2];
  const float* feats_t = (const float*)d_in[3];
  const float* w0      = (const float*)d_in[4];
  const float* b0      = (const float*)d_in[5];
  const float* gamma0  = (const float*)d_in[6];
  const float* beta0   = (const float*)d_in[7];
  const float* w1      = (const float*)d_in[8];
  const float* b1      = (const float*)d_in[9];
  const float* gamma1  = (const float*)d_in[10];
  const float* beta1   = (const float*)d_in[11];
  float* out = (float*)d_out;

  char* ws = (char*)d_ws;
  size_t off = 0;
  auto alloc = [&](size_t bytes) -> void* {
    void* p = ws + off;
    off = (off + bytes + 255) & ~(size_t)255;
    return p;
  };
  float*  wgt     = (float*) alloc((size_t)M_*3*4);
  int*    widx    = (int*)   alloc((size_t)M_*3*4);
  double* tgtp    = (double*)alloc((size_t)(B_*S_/2)*32);
  // union region: {pd, pi} (dead after k_merge) overlaid by {features/x1}
  char*   uni     = (char*)  alloc((size_t)M_*CIN_*2);
  float*  pd      = (float*) uni;
  int*    pi      = (int*)  (uni + (size_t)M_*NCH_*3*4);
  bf16_t* features= (bf16_t*)uni;
  bf16_t* w0b     = (bf16_t*)alloc((size_t)C0_*CIN_*2);
  bf16_t* w1b     = (bf16_t*)alloc((size_t)C1_*C0_*2);
  bf16_t* x0      = (bf16_t*)alloc((size_t)M_*C0_*2);
  float*  psum0   = (float*) alloc(512*128*4);
  float*  psq0    = (float*) alloc(512*128*4);
  float*  scale0  = (float*) alloc(256*4);
  float*  shift0  = (float*) alloc(256*4);
  float*  psum1   = (float*) alloc(256*128*4);
  float*  psq1    = (float*) alloc(256*128*4);
  float*  scale1  = (float*) alloc(128*4);
  float*  shift1  = (float*) alloc(128*4);
  bf16_t* x1      = features;                 // features dead after gemm1 -> reuse

  k_misc  <<<dim3(384), dim3(256), 0, stream>>>(xyz_t, tgtp, w0, w1, w0b, w1b);
  k_knn   <<<dim3(N_/256, NCH_, B_), dim3(256), 0, stream>>>(xyz_s, tgtp, pd, pi);
  k_merge <<<dim3(M_/256), dim3(256), 0, stream>>>(pd, pi, wgt, widx);
  k_gather<<<dim3(M_/8), dim3(256), 0, stream>>>(feats_s, feats_t, wgt, widx, features);
  k_gemm1 <<<dim3(M_/128, C0_/128), dim3(256), 0, stream>>>(features, w0b, b0, x0, psum0, psq0);
  k_fin0  <<<dim3(256), dim3(256), 0, stream>>>(psum0, psq0, gamma0, beta0, scale0, shift0);
  k_gemm2 <<<dim3(M_/128), dim3(256), 0, stream>>>(x0, w1b, scale0, shift0, b1, x1, psum1, psq1);
  k_fin1  <<<dim3(128), dim3(256), 0, stream>>>(psum1, psq1, gamma1, beta1, scale1, shift1);
  k_apply <<<dim3(M_*C1_/8/256), dim3(256), 0, stream>>>(x1, scale1, shift1, out);
}